// Round 2
// baseline (693.813 us; speedup 1.0000x reference)
//
#include <hip/hip_runtime.h>
#include <hip/hip_bf16.h>
#include <stdint.h>

typedef __bf16 bf16x8 __attribute__((ext_vector_type(8)));
typedef float f32x4 __attribute__((ext_vector_type(4)));
typedef unsigned short u16;
typedef u16 u16x8 __attribute__((ext_vector_type(8)));
typedef u16 u16x4 __attribute__((ext_vector_type(4)));

// Problem constants: B=16, C=32, H=W=128, K=8 -> P=256, M=K=8192, N=1024.
#define MD 8192
#define KD 8192
#define ND 1024
#define KSPLIT 2
#define KHALF (KD / KSPLIT)

__device__ __forceinline__ u16 f32_to_bf16(float f) {
  uint32_t u = __float_as_uint(f);
  u += 0x7FFFu + ((u >> 16) & 1u);   // round-to-nearest-even
  return (u16)(u >> 16);
}

__device__ __forceinline__ void load_lds16(const void* g, void* l) {
  __builtin_amdgcn_global_load_lds(
      (const __attribute__((address_space(1))) void*)g,
      (__attribute__((address_space(3))) void*)l, 16, 0, 0);
}

// ---- kernel 1: g (8192x8192 fp32, row-major [o][i]) -> bf16, same layout ----
__global__ __launch_bounds__(256) void convert_g(const float* __restrict__ g,
                                                 u16* __restrict__ gb) {
  size_t t = (size_t)blockIdx.x * 256 + threadIdx.x;   // 8388608 threads x 8 elems
  const float4* gp = (const float4*)g + t * 2;
  float4 a = gp[0], b = gp[1];
  u16x8 r;
  r[0] = f32_to_bf16(a.x); r[1] = f32_to_bf16(a.y);
  r[2] = f32_to_bf16(a.z); r[3] = f32_to_bf16(a.w);
  r[4] = f32_to_bf16(b.x); r[5] = f32_to_bf16(b.y);
  r[6] = f32_to_bf16(b.z); r[7] = f32_to_bf16(b.w);
  *((u16x8*)gb + t) = r;
}

// ---- kernel 2: build B^T (1024 cols x 8192 K, K contiguous), coalesced ----
// One wave per (n, ci, hy): reads 8 rows x 128 floats of x (coalesced float4),
// transposes via padded LDS, writes 64 chunks of 16 contiguous bf16 (32 B).
__global__ __launch_bounds__(256) void build_b(const float* __restrict__ x,
                                               u16* __restrict__ bt) {
  __shared__ u16 lds[4][8 * 136];                      // +8 u16 row pad
  const int wave = threadIdx.x >> 6;
  const int lane = threadIdx.x & 63;
  const int w = blockIdx.x * 4 + wave;                 // 0..8191
  const int n = w >> 9, rem = w & 511;
  const int ci = rem >> 4, hy = rem & 15;
  const float* src = x + ((size_t)((n << 5) + ci) * 128 + (hy << 3)) * 128;
  u16* l = lds[wave];
#pragma unroll
  for (int q = 0; q < 4; ++q) {
    float4 v = ((const float4*)src)[lane + q * 64];    // coalesced 1KB/instr
    const int f = (lane << 2) + (q << 8);              // linear elem idx 0..1023
    u16x4 c;
    c[0] = f32_to_bf16(v.x); c[1] = f32_to_bf16(v.y);
    c[2] = f32_to_bf16(v.z); c[3] = f32_to_bf16(v.w);
    *(u16x4*)(l + (f >> 7) * 136 + (f & 127)) = c;     // row = kk, padded
  }
  __syncthreads();
  const int kk = lane >> 3, j = lane & 7;
  u16x8 o0, o1;
#pragma unroll
  for (int wx = 0; wx < 8; ++wx) o0[wx] = l[kk * 136 + (wx << 3) + j];
#pragma unroll
  for (int wx = 8; wx < 16; ++wx) o1[wx - 8] = l[kk * 136 + (wx << 3) + j];
  u16* dst = bt + (size_t)((n << 6) + (kk << 3) + j) * KD + (ci << 8) + (hy << 4);
  *(u16x8*)dst = o0;
  *(u16x8*)(dst + 8) = o1;
}

// ---- kernel 3: out = x (residual init for the atomic split-K epilogue) ----
__global__ __launch_bounds__(256) void init_out(const float* __restrict__ x,
                                                float* __restrict__ out) {
  size_t t = (size_t)blockIdx.x * 256 + threadIdx.x;   // 2097152 threads x float4
  ((float4*)out)[t] = ((const float4*)x)[t];
}

// ---- kernel 4: C += A * B^T, split-K x2, XCD-pinned swizzle, atomic epilogue ----
__global__ __launch_bounds__(256) void gemm_bt(
    const u16* __restrict__ A,    // 8192 x 8192 bf16
    const u16* __restrict__ B,    // 1024 x 8192 bf16 (B^T)
    float* __restrict__ out) {
  __shared__ u16 As[128 * 32];
  __shared__ u16 Bs[128 * 32];
  const int tid  = threadIdx.x;
  const int wave = tid >> 6;
  const int lane = tid & 63;

  // swizzle: 8 N-blocks of one (M-tile, K-half) slice share lin%8 -> same XCD L2
  const int lin = blockIdx.x;          // 0..1023
  const int xcd = lin & 7;
  const int jj_ = lin >> 3;            // 0..127
  const int nb = jj_ & 7;
  const int s = (((jj_ >> 3) << 3) | xcd);   // 0..127 slice id
  const int kh = s & 1;
  const int mb = s >> 1;               // 0..63
  const int m0 = mb << 7;
  const int n0 = nb << 7;
  const int kbase = kh * KHALF;

  const int mst = (wave << 4) + (lane >> 2);
  const int kst = (lane & 3) << 3;
  const u16* gA0 = A + (size_t)(m0 + mst) * KD + kbase + kst;
  const u16* gA1 = gA0 + (size_t)64 * KD;
  const u16* gB0 = B + (size_t)(n0 + mst) * KD + kbase + kst;
  const u16* gB1 = gB0 + (size_t)64 * KD;
  char* ldsA = (char*)As + (wave << 10);
  char* ldsB = (char*)Bs + (wave << 10);

  const int wm = wave & 1, wn = wave >> 1;
  const int lm = lane & 15;
  const int kg = (lane >> 4) << 3;
  const u16* fA = As + ((wm << 6) + lm) * 32 + kg;
  const u16* fB = Bs + ((wn << 6) + lm) * 32 + kg;

  f32x4 acc[4][4];
#pragma unroll
  for (int i = 0; i < 4; ++i)
#pragma unroll
    for (int j = 0; j < 4; ++j)
      acc[i][j] = (f32x4){0.f, 0.f, 0.f, 0.f};

  for (int kt = 0; kt < KHALF / 32; ++kt) {
    const int k0 = kt << 5;
    __syncthreads();
    load_lds16(gA0 + k0, ldsA);
    load_lds16(gA1 + k0, ldsA + 4096);
    load_lds16(gB0 + k0, ldsB);
    load_lds16(gB1 + k0, ldsB + 4096);
    __syncthreads();
    bf16x8 av[4], bv[4];
#pragma unroll
    for (int i = 0; i < 4; ++i) {
      av[i] = *(const bf16x8*)(fA + i * 16 * 32);
      bv[i] = *(const bf16x8*)(fB + i * 16 * 32);
    }
#pragma unroll
    for (int i = 0; i < 4; ++i)
#pragma unroll
      for (int j = 0; j < 4; ++j)
        acc[i][j] = __builtin_amdgcn_mfma_f32_16x16x32_bf16(av[i], bv[j], acc[i][j], 0, 0, 0);
  }

  // epilogue: C/D layout col=lane&15, row=(lane>>4)*4+reg  [m89-verified]
  // inverse im2col permute + atomicAdd into residual-initialized out
  const int r4 = (lane >> 4) << 2;
#pragma unroll
  for (int i = 0; i < 4; ++i) {
    const int obase = m0 + (wm << 6) + (i << 4) + r4;
#pragma unroll
    for (int j = 0; j < 4; ++j) {
      const int cg = n0 + (wn << 6) + (j << 4) + lm;
      const int n = cg >> 6, kk = (cg >> 3) & 7, jc = cg & 7;
#pragma unroll
      for (int reg = 0; reg < 4; ++reg) {
        const int oo = obase + reg;
        const int co = oo >> 8, hy = (oo >> 4) & 15, wx = oo & 15;
        const size_t idx =
            ((size_t)((n << 5) + co) * 128 + (hy << 3) + kk) * 128 + (wx << 3) + jc;
        atomicAdd(&out[idx], acc[i][j][reg]);
      }
    }
  }
}

extern "C" void kernel_launch(void* const* d_in, const int* in_sizes, int n_in,
                              void* d_out, int out_size, void* d_ws, size_t ws_size,
                              hipStream_t stream) {
  const float* x = (const float*)d_in[0];       // (16,32,128,128) fp32
  const float* g = (const float*)d_in[1];       // (8192,8192) fp32
  float* out = (float*)d_out;                   // (16,32,128,128) fp32

  u16* gb = (u16*)d_ws;                         // 8192*8192 bf16 = 128 MiB
  u16* bt = gb + (size_t)MD * KD;               // 1024*8192 bf16 = 16 MiB

  convert_g<<<32768, 256, 0, stream>>>(g, gb);
  build_b<<<2048, 256, 0, stream>>>(x, bt);
  init_out<<<8192, 256, 0, stream>>>(x, out);
  gemm_bt<<<1024, 256, 0, stream>>>(gb, bt, out);
}

// Round 3
// 585.708 us; speedup vs baseline: 1.1846x; 1.1846x over previous
//
#include <hip/hip_runtime.h>
#include <hip/hip_bf16.h>
#include <stdint.h>

typedef __bf16 bf16x8 __attribute__((ext_vector_type(8)));
typedef float f32x4 __attribute__((ext_vector_type(4)));
typedef unsigned short u16;
typedef u16 u16x8 __attribute__((ext_vector_type(8)));
typedef u16 u16x4 __attribute__((ext_vector_type(4)));

// Problem constants: B=16, C=32, H=W=128, K=8 -> P=256, M=K=8192, N=1024.
#define MD 8192
#define KD 8192
#define ND 1024

__device__ __forceinline__ u16 f32_to_bf16(float f) {
  uint32_t u = __float_as_uint(f);
  u += 0x7FFFu + ((u >> 16) & 1u);   // round-to-nearest-even
  return (u16)(u >> 16);
}

__device__ __forceinline__ void load_lds16(const void* g, void* l) {
  __builtin_amdgcn_global_load_lds(
      (const __attribute__((address_space(1))) void*)g,
      (__attribute__((address_space(3))) void*)l, 16, 0, 0);
}

// ---- kernel 1: g (8192x8192 fp32) -> bf16, dense 1 float4 / thread ----
__global__ __launch_bounds__(256) void convert_g(const float* __restrict__ g,
                                                 u16* __restrict__ gb) {
  size_t t = (size_t)blockIdx.x * 256 + threadIdx.x;   // 16777216 threads
  float4 a = ((const float4*)g)[t];
  u16x4 r;
  r[0] = f32_to_bf16(a.x); r[1] = f32_to_bf16(a.y);
  r[2] = f32_to_bf16(a.z); r[3] = f32_to_bf16(a.w);
  ((u16x4*)gb)[t] = r;
}

// ---- kernel 2: build B^T (1024 cols x 8192 K, K contiguous), coalesced ----
__global__ __launch_bounds__(256) void build_b(const float* __restrict__ x,
                                               u16* __restrict__ bt) {
  __shared__ u16 lds[4][8 * 136];                      // +8 u16 row pad
  const int wave = threadIdx.x >> 6;
  const int lane = threadIdx.x & 63;
  const int w = blockIdx.x * 4 + wave;                 // 0..8191
  const int n = w >> 9, rem = w & 511;
  const int ci = rem >> 4, hy = rem & 15;
  const float* src = x + ((size_t)((n << 5) + ci) * 128 + (hy << 3)) * 128;
  u16* l = lds[wave];
#pragma unroll
  for (int q = 0; q < 4; ++q) {
    float4 v = ((const float4*)src)[lane + q * 64];    // coalesced 1KB/instr
    const int f = (lane << 2) + (q << 8);              // linear elem idx 0..1023
    u16x4 c;
    c[0] = f32_to_bf16(v.x); c[1] = f32_to_bf16(v.y);
    c[2] = f32_to_bf16(v.z); c[3] = f32_to_bf16(v.w);
    *(u16x4*)(l + (f >> 7) * 136 + (f & 127)) = c;     // row = kk, padded
  }
  __syncthreads();
  const int kk = lane >> 3, j = lane & 7;
  u16x8 o0, o1;
#pragma unroll
  for (int wx = 0; wx < 8; ++wx) o0[wx] = l[kk * 136 + (wx << 3) + j];
#pragma unroll
  for (int wx = 8; wx < 16; ++wx) o1[wx - 8] = l[kk * 136 + (wx << 3) + j];
  u16* dst = bt + (size_t)((n << 6) + (kk << 3) + j) * KD + (ci << 8) + (hy << 4);
  *(u16x8*)dst = o0;
  *(u16x8*)(dst + 8) = o1;
}

// ---- kernel 3: C = A*B^T, 128x64 tiles (1024 blocks, 4 blocks/CU), ----
// ---- XCD-pinned swizzle, direct epilogue with fused permute+residual ----
__global__ __launch_bounds__(256, 4) void gemm_bt(
    const u16* __restrict__ A,    // 8192 x 8192 bf16
    const u16* __restrict__ B,    // 1024 x 8192 bf16 (B^T)
    const float* __restrict__ X,  // residual
    float* __restrict__ out) {
  __shared__ u16 As[128 * 32];    // 8 KB
  __shared__ u16 Bs[64 * 32];     // 4 KB
  const int tid  = threadIdx.x;
  const int wave = tid >> 6;
  const int lane = tid & 63;

  // swizzle: the 16 N-blocks sharing an M-tile get lin%8 == mb%8 -> one XCD L2
  const int lin = blockIdx.x;          // 0..1023
  const int mb = lin & 63;             // M-tile 0..63
  const int nb = lin >> 6;             // N-tile 0..15
  const int m0 = mb << 7;
  const int n0 = nb << 6;

  // staging: thread -> one 16B chunk per instr (A: 2 instrs, B: 1)
  const int mst = (wave << 4) + (lane >> 2);           // 0..63
  const int kst = (lane & 3) << 3;                     // elem 0,8,16,24
  const u16* gA0 = A + (size_t)(m0 + mst) * KD + kst;
  const u16* gA1 = gA0 + (size_t)64 * KD;
  const u16* gB0 = B + (size_t)(n0 + mst) * KD + kst;
  char* ldsA = (char*)As + (wave << 10);               // wave-uniform base
  char* ldsB = (char*)Bs + (wave << 10);

  const int wm = wave & 1, wn = wave >> 1;             // wave tile 64x32
  const int lm = lane & 15;
  const int kg = (lane >> 4) << 3;                     // k elem 0,8,16,24
  const u16* fA = As + ((wm << 6) + lm) * 32 + kg;
  const u16* fB = Bs + ((wn << 5) + lm) * 32 + kg;

  f32x4 acc[4][2];
#pragma unroll
  for (int i = 0; i < 4; ++i)
#pragma unroll
    for (int j = 0; j < 2; ++j)
      acc[i][j] = (f32x4){0.f, 0.f, 0.f, 0.f};

  for (int kt = 0; kt < KD / 32; ++kt) {
    const int k0 = kt << 5;
    __syncthreads();
    load_lds16(gA0 + k0, ldsA);
    load_lds16(gA1 + k0, ldsA + 4096);
    load_lds16(gB0 + k0, ldsB);
    __syncthreads();
    bf16x8 av[4], bv[2];
#pragma unroll
    for (int i = 0; i < 4; ++i) av[i] = *(const bf16x8*)(fA + i * 16 * 32);
#pragma unroll
    for (int j = 0; j < 2; ++j) bv[j] = *(const bf16x8*)(fB + j * 16 * 32);
#pragma unroll
    for (int i = 0; i < 4; ++i)
#pragma unroll
      for (int j = 0; j < 2; ++j)
        acc[i][j] = __builtin_amdgcn_mfma_f32_16x16x32_bf16(av[i], bv[j], acc[i][j], 0, 0, 0);
  }

  // epilogue: C/D layout col=lane&15, row=(lane>>4)*4+reg  [m89-verified]
  const int r4 = (lane >> 4) << 2;
#pragma unroll
  for (int i = 0; i < 4; ++i) {
    const int obase = m0 + (wm << 6) + (i << 4) + r4;
#pragma unroll
    for (int j = 0; j < 2; ++j) {
      const int cg = n0 + (wn << 5) + (j << 4) + lm;
      const int n = cg >> 6, kk = (cg >> 3) & 7, jc = cg & 7;
#pragma unroll
      for (int reg = 0; reg < 4; ++reg) {
        const int oo = obase + reg;
        const int co = oo >> 8, hy = (oo >> 4) & 15, wx = oo & 15;
        const size_t idx =
            ((size_t)((n << 5) + co) * 128 + (hy << 3) + kk) * 128 + (wx << 3) + jc;
        out[idx] = acc[i][j][reg] + X[idx];
      }
    }
  }
}

extern "C" void kernel_launch(void* const* d_in, const int* in_sizes, int n_in,
                              void* d_out, int out_size, void* d_ws, size_t ws_size,
                              hipStream_t stream) {
  const float* x = (const float*)d_in[0];       // (16,32,128,128) fp32
  const float* g = (const float*)d_in[1];       // (8192,8192) fp32
  float* out = (float*)d_out;                   // (16,32,128,128) fp32

  u16* gb = (u16*)d_ws;                         // 8192*8192 bf16 = 128 MiB
  u16* bt = gb + (size_t)MD * KD;               // 1024*8192 bf16 = 16 MiB

  convert_g<<<65536, 256, 0, stream>>>(g, gb);
  build_b<<<2048, 256, 0, stream>>>(x, bt);
  gemm_bt<<<1024, 256, 0, stream>>>(gb, bt, x, out);
}